// Round 1
// baseline (343.042 us; speedup 1.0000x reference)
//
#include <hip/hip_runtime.h>
#include <hip/hip_cooperative_groups.h>

namespace cg = cooperative_groups;

// Problem constants (fixed by the reference)
#define NGRAPH 16
#define NPG    4096
#define KCL    64
#define DF     128
#define NTOT   65536
#define NEDGE  1048576

// output layout (floats)
//   out[0,131072) | out_adj[131072,196608) | link 196608 | ent 196609
//   batch[196610,197634) | batch_ptr[197634,197651)

// ws layout (bytes) — everything plain-stored, nothing needs zeroing
#define WS_CLUS   0         // u8[65536]
#define WS_CNT    65536     // int[1024]
#define WS_START  69632     // int[1024]
#define WS_CROSS  73728     // float[256]
#define WS_ASQ    74752     // float[256]
#define WS_ORDER  75776     // u16[65536]
#define WS_ADJP   206848    // float[256][4096]

// ---------------------------------------------------------------------------
// Single fused cooperative kernel: 256 blocks x 1024 threads (1 block/CU).
// Phase 1: assign (4 x 64-node sub-tiles per block, proven R4 inner loop)
// Phase 2: edge slices (all blocks) + counting sorts (blocks 0..15)
// Phase 3: pooling (4 units/block) + adj reduce + finalize
// LDS phases overlap via a union (max = phase 1, ~140 KB, 1 block/CU).
// ---------------------------------------------------------------------------

struct P1 {
    float xs[4][64 * 132];    // 4 sub-tiles, 64 nodes x 128 (pad 132)
    float cv[4][4][64];
    int   ck[4][4][64];
};
struct P2 {
    int   hist[KCL];
    int   offs[KCL];
    float adj[KCL * KCL];     // 16 KB
    unsigned char cl[NPG];    // 4 KB
    float redc[16], redq[16];
};
struct P3 {
    unsigned short ord[4][NPG];  // 32 KB
    float4 part[4][8][32];       // 16 KB
};
union ShU { P1 p1; P2 p2; P3 p3; };

__global__ __launch_bounds__(1024) void fused_kernel(
    const float* __restrict__ x, const float* __restrict__ W,
    const float* __restrict__ bias, const float* __restrict__ gum,
    const float* __restrict__ ew, const int* __restrict__ ei,
    float* __restrict__ out, char* __restrict__ wsb)
{
    __shared__ ShU sh;
    cg::grid_group grid = cg::this_grid();

    unsigned char*  clus   = (unsigned char*) (wsb + WS_CLUS);
    int*            counts = (int*)           (wsb + WS_CNT);
    int*            starts = (int*)           (wsb + WS_START);
    float*          crossp = (float*)         (wsb + WS_CROSS);
    float*          asqp   = (float*)         (wsb + WS_ASQ);
    unsigned short* order  = (unsigned short*)(wsb + WS_ORDER);
    float*          adjp   = (float*)         (wsb + WS_ADJP);

    const int tid = threadIdx.x;
    const int blk = blockIdx.x;

    //======================= phase 1: assign =======================
    {
        const int sub  = tid >> 8;          // 0..3 sub-block
        const int t    = tid & 255;
        const int wave = (tid >> 6) & 3;    // wave within sub-block
        const int lane = tid & 63;
        const int n0   = (blk << 8) + (sub << 6);
        float* xs = sh.p1.xs[sub];

        {
            const float4* xg = (const float4*)(x + (size_t)n0 * DF);
            #pragma unroll
            for (int i = 0; i < 8; ++i) {
                int j4 = t + (i << 8); int j = j4 << 2;
                float4 v = xg[j4];
                *(float4*)&xs[(j >> 7) * 132 + (j & 127)] = v;
            }
        }
        __syncthreads();

        const int k0 = __builtin_amdgcn_readfirstlane(wave << 4);  // wave-uniform
        float acc[16];
        #pragma unroll
        for (int kk = 0; kk < 16; ++kk) acc[kk] = bias[k0 + kk];

        #pragma unroll 4
        for (int dc = 0; dc < 32; ++dc) {
            float4 xv = *(const float4*)&xs[lane * 132 + (dc << 2)];
            const float* wp = W + (dc << 8) + k0;      // wave-uniform -> s_load
            #pragma unroll
            for (int kk = 0; kk < 16; ++kk) {
                float a = acc[kk];
                a = fmaf(xv.x, wp[kk],        a);
                a = fmaf(xv.y, wp[64  + kk],  a);
                a = fmaf(xv.z, wp[128 + kk],  a);
                a = fmaf(xv.w, wp[192 + kk],  a);
                acc[kk] = a;
            }
        }

        // gumbel + per-wave argmax (first-max tie-break, k ascending)
        const float* gp = gum + ((size_t)(n0 + lane) << 6) + k0;
        float best = -3.4e38f; int bestk = k0;
        #pragma unroll
        for (int q = 0; q < 4; ++q) {
            float4 u = *(const float4*)(gp + (q << 2));
            float uv[4] = {u.x, u.y, u.z, u.w};
            #pragma unroll
            for (int r = 0; r < 4; ++r) {
                float g = -__logf(-__logf(uv[r]));
                float v = acc[(q << 2) + r] + g;
                if (v > best) { best = v; bestk = k0 + (q << 2) + r; }
            }
        }
        sh.p1.cv[sub][wave][lane] = best;
        sh.p1.ck[sub][wave][lane] = bestk;
        __syncthreads();

        if (t < 64) {   // combine 4 waves (k-chunks ascending => global first-max)
            float bv = sh.p1.cv[sub][0][t]; int bk = sh.p1.ck[sub][0][t];
            #pragma unroll
            for (int w2 = 1; w2 < 4; ++w2) {
                float v = sh.p1.cv[sub][w2][t];
                if (v > bv) { bv = v; bk = sh.p1.ck[sub][w2][t]; }
            }
            clus[n0 + t] = (unsigned char)bk;
        }
    }
    __syncthreads();
    __threadfence();
    grid.sync();

    //======================= phase 2: sort + edges =======================
    {
        if (blk < 16) {
            //---------------- counting sort for graph blk ----------------
            const int bg = blk;
            if (tid < KCL) sh.p2.hist[tid] = 0;
            __syncthreads();
            unsigned char c[4];
            #pragma unroll
            for (int i = 0; i < 4; ++i) {
                c[i] = clus[(bg << 12) + tid + (i << 10)];
                atomicAdd(&sh.p2.hist[c[i]], 1);
            }
            __syncthreads();
            if (tid < KCL) {
                int v = sh.p2.hist[tid], inc = v;
                #pragma unroll
                for (int off = 1; off < 64; off <<= 1) {
                    int tt = __shfl_up(inc, off);
                    if (tid >= off) inc += tt;
                }
                int excl = inc - v;
                sh.p2.offs[tid] = excl;
                counts[(bg << 6) + tid] = v;
                starts[(bg << 6) + tid] = excl;
            }
            __syncthreads();
            #pragma unroll
            for (int i = 0; i < 4; ++i) {
                int p = atomicAdd(&sh.p2.offs[c[i]], 1);
                order[(bg << 12) + p] = (unsigned short)(tid + (i << 10));
            }
            __syncthreads();
        }

        //---------------- edge slice blk (4096 edges) ----------------
        const int eb = blk;
        const int bg = eb >> 4;
        ((float4*)sh.p2.adj)[tid] = make_float4(0.f, 0.f, 0.f, 0.f);
        ((int*)sh.p2.cl)[tid] = ((const int*)(clus + (size_t)bg * NPG))[tid];
        __syncthreads();

        const int e0 = eb << 12;
        float csum = 0.f, qsum = 0.f;
        #pragma unroll
        for (int it = 0; it < 4; ++it) {
            const int e = e0 + (it << 10) + tid;
            const int s = ei[e]         & (NPG - 1);   // graphs are 4096-aligned
            const int d = ei[NEDGE + e] & (NPG - 1);
            const float w = ew[e];
            const int ks = sh.p2.cl[s], kd = sh.p2.cl[d];
            atomicAdd(&sh.p2.adj[(ks << 6) + kd], w);
            csum += (ks == kd) ? w : 0.f;
            qsum += w * w;
        }
        #pragma unroll
        for (int off = 32; off > 0; off >>= 1) {
            csum += __shfl_down(csum, off);
            qsum += __shfl_down(qsum, off);
        }
        const int lane = tid & 63, wv = tid >> 6;
        if (lane == 0) { sh.p2.redc[wv] = csum; sh.p2.redq[wv] = qsum; }
        __syncthreads();   // also guarantees all LDS atomics into adj are done
        if (tid == 0) {
            float cs = 0.f, qs = 0.f;
            #pragma unroll
            for (int i = 0; i < 16; ++i) { cs += sh.p2.redc[i]; qs += sh.p2.redq[i]; }
            crossp[eb] = cs;
            asqp[eb]   = qs;
        }
        ((float4*)(adjp + ((size_t)eb << 12)))[tid] = ((const float4*)sh.p2.adj)[tid];
    }
    __syncthreads();
    __threadfence();
    grid.sync();

    //======================= phase 3: pool + reduce + finalize ===========
    {
        //---------------- segment-sum pooling, 4 (graph,cluster) units/block
        const int sub = tid >> 8, t = tid & 255;
        const int u = (blk << 2) + sub;            // 0..1023 == (bg<<6)+k
        const int bg = u >> 6, k = u & 63;
        const int cnt = counts[u], start = starts[u];
        unsigned short* ordS = sh.p3.ord[sub];
        for (int i = t; i < cnt; i += 256)
            ordS[i] = order[((size_t)bg << 12) + start + i];
        __syncthreads();
        const int grp = t >> 5, l32 = t & 31;
        float4 acc = make_float4(0.f, 0.f, 0.f, 0.f);
        for (int i = grp; i < cnt; i += 8) {
            const float4* row = (const float4*)(x + (((size_t)(bg << 12) + ordS[i]) << 7));
            float4 v = row[l32];
            acc.x += v.x; acc.y += v.y; acc.z += v.z; acc.w += v.w;
        }
        sh.p3.part[sub][grp][l32] = acc;
        __syncthreads();
        if (grp == 0) {
            float4 s = sh.p3.part[sub][0][l32];
            #pragma unroll
            for (int g = 1; g < 8; ++g) {
                float4 p = sh.p3.part[sub][g][l32];
                s.x += p.x; s.y += p.y; s.z += p.z; s.w += p.w;
            }
            ((float4*)(out + (((size_t)bg << 13) + (k << 7))))[l32] = s;
        }
    }

    //---------------- out_adj: reduce the 16 slice-partials ----------------
    if (tid < 256) {
        const int cell = (blk << 8) + tid;          // 0..65535
        const int bg = cell >> 12, j = cell & 4095;
        float s = 0.f;
        #pragma unroll
        for (int sl = 0; sl < 16; ++sl)
            s += adjp[((size_t)((bg << 4) + sl) << 12) + j];
        out[131072 + cell] = s;
    }

    //---------------- losses + constant outputs ----------------------------
    if (blk == 0) {
        if (tid < 64) {
            float link = 0.f;
            if (tid < 16) {
                const int bg = tid;
                float s2 = 0.f;
                #pragma unroll 8
                for (int k2 = 0; k2 < 64; ++k2) {
                    float c = (float)counts[(bg << 6) + k2];
                    s2 = fmaf(c, c, s2);
                }
                float cs = 0.f, as = 0.f;
                #pragma unroll
                for (int sl = 0; sl < 16; ++sl) {
                    cs += crossp[(bg << 4) + sl];
                    as += asqp[(bg << 4) + sl];
                }
                link = sqrtf(fmaxf(as - 2.f * cs + s2, 0.f)) * (1.f / 65536.f);
            }
            // wave-synchronous sum of lanes 0..15 into lane 0 (no barrier)
            #pragma unroll
            for (int off = 8; off > 0; off >>= 1) link += __shfl_down(link, off);
            if (tid == 0) {
                out[196608] = link * (1.f / 16.f);   // link_loss
                out[196609] = 0.f;                   // entropy_loss (exact 0)
            }
        }
        out[196610 + tid] = (float)(tid >> 6);                 // batch (1024)
        if (tid < 17) out[197634 + tid] = (float)(tid << 6);   // batch_ptr_out
    }
}

extern "C" void kernel_launch(void* const* d_in, const int* in_sizes, int n_in,
                              void* d_out, int out_size, void* d_ws, size_t ws_size,
                              hipStream_t stream) {
    const float* x    = (const float*)d_in[0];
    const float* W    = (const float*)d_in[1];
    const float* bias = (const float*)d_in[2];
    const float* ew   = (const float*)d_in[3];
    const float* gum  = (const float*)d_in[4];
    const int*   ei   = (const int*)  d_in[5];
    // d_in[6] = batch_ptr (int64) — unused, graphs are equal-sized

    float* out = (float*)d_out;
    char*  wsb = (char*)d_ws;

    void* args[8] = { (void*)&x, (void*)&W, (void*)&bias, (void*)&gum,
                      (void*)&ew, (void*)&ei, (void*)&out, (void*)&wsb };
    hipLaunchCooperativeKernel(fused_kernel, dim3(256), dim3(1024),
                               args, 0, stream);
}

// Round 2
// 132.879 us; speedup vs baseline: 2.5816x; 2.5816x over previous
//
#include <hip/hip_runtime.h>

// Problem constants (fixed by the reference)
#define NGRAPH 16
#define NPG    4096
#define KCL    64
#define DF     128
#define NTOT   65536
#define NEDGE  1048576

// output layout (floats)
//   out[0,131072) | out_adj[131072,196608) | link 196608 | ent 196609
//   batch[196610,197634) | batch_ptr[197634,197651)

// ws layout (bytes) — everything plain-stored, nothing needs zeroing
#define WS_CLUS   0         // u8[65536]
#define WS_CNT    65536     // int[1024]
#define WS_START  69632     // int[1024]
#define WS_CROSS  73728     // float[256]
#define WS_ASQ    74752     // float[256]
#define WS_ORDER  75776     // u16[65536]

// ---------------------------------------------------------------------------
// K1: per-node argmax assignment (logits GEMM + gumbel), writes clus.
// Proven design: 64-node LDS tile, 4 waves x 16 clusters, acc[16]/lane.
// Blocks 0..63 additionally zero the out_adj region (K2 atomics into it).
// ---------------------------------------------------------------------------
__global__ __launch_bounds__(256) void assign_kernel(
    const float* __restrict__ x, const float* __restrict__ W,
    const float* __restrict__ bias, const float* __restrict__ gum,
    unsigned char* __restrict__ clus, float* __restrict__ out)
{
    __shared__ __align__(16) float xs[64 * 132];   // 64 nodes x 128, pad 132
    __shared__ float cand_v[4][64];
    __shared__ int   cand_k[4][64];

    const int tid = threadIdx.x, wave = tid >> 6, lane = tid & 63;
    const int n0 = blockIdx.x * 64;

    // zero out_adj (65536 floats) across blocks 0..63, one float4/thread
    if (blockIdx.x < 64)
        ((float4*)(out + 131072))[(blockIdx.x << 8) + tid] =
            make_float4(0.f, 0.f, 0.f, 0.f);

    {
        const float4* xg = (const float4*)(x + (size_t)n0 * DF);
        #pragma unroll
        for (int i = 0; i < 8; ++i) {
            int j4 = tid + i * 256; int j = j4 << 2;
            float4 v = xg[j4];
            *(float4*)&xs[(j >> 7) * 132 + (j & 127)] = v;
        }
    }
    __syncthreads();

    const int k0 = __builtin_amdgcn_readfirstlane(wave << 4);  // wave-uniform
    float acc[16];
    #pragma unroll
    for (int kk = 0; kk < 16; ++kk) acc[kk] = bias[k0 + kk];

    #pragma unroll 4
    for (int dc = 0; dc < 32; ++dc) {
        float4 xv = *(const float4*)&xs[lane * 132 + (dc << 2)];
        const float* wp = W + (dc << 8) + k0;      // wave-uniform -> s_load
        #pragma unroll
        for (int kk = 0; kk < 16; ++kk) {
            float a = acc[kk];
            a = fmaf(xv.x, wp[kk],        a);
            a = fmaf(xv.y, wp[64  + kk],  a);
            a = fmaf(xv.z, wp[128 + kk],  a);
            a = fmaf(xv.w, wp[192 + kk],  a);
            acc[kk] = a;
        }
    }

    // gumbel + per-wave argmax (first-max tie-break, k ascending)
    const float* gp = gum + ((size_t)(n0 + lane) << 6) + k0;
    float best = -3.4e38f; int bestk = k0;
    #pragma unroll
    for (int q = 0; q < 4; ++q) {
        float4 u = *(const float4*)(gp + (q << 2));
        float uv[4] = {u.x, u.y, u.z, u.w};
        #pragma unroll
        for (int r = 0; r < 4; ++r) {
            float g = -__logf(-__logf(uv[r]));
            float v = acc[(q << 2) + r] + g;
            if (v > best) { best = v; bestk = k0 + (q << 2) + r; }
        }
    }
    cand_v[wave][lane] = best;
    cand_k[wave][lane] = bestk;
    __syncthreads();

    if (tid < 64) {   // combine 4 waves (k-chunks ascending => global first-max)
        float bv = cand_v[0][tid]; int bk = cand_k[0][tid];
        #pragma unroll
        for (int w2 = 1; w2 < 4; ++w2) {
            float v = cand_v[w2][tid];
            if (v > bv) { bv = v; bk = cand_k[w2][tid]; }
        }
        clus[n0 + tid] = (unsigned char)bk;
    }
}

// ---------------------------------------------------------------------------
// K2: sort (blocks 0..15, one graph each)  ||  edge slices (blocks 16..271).
// Both depend only on clus; internally independent.
// Edge slices push their LDS adj tile straight into out_adj (global atomics,
// destination zeroed by K1) — removes the adjp partial round-trip.
// ---------------------------------------------------------------------------
__global__ __launch_bounds__(1024) void sortedge_kernel(
    const unsigned char* __restrict__ clus,
    const int* __restrict__ ei, const float* __restrict__ ew,
    int* __restrict__ counts, int* __restrict__ starts,
    unsigned short* __restrict__ order,
    float* __restrict__ out, float* __restrict__ crossp,
    float* __restrict__ asqp)
{
    __shared__ int   hist[KCL];
    __shared__ int   offs[KCL];
    __shared__ float adj[KCL * KCL];       // 16 KB
    __shared__ unsigned char cl[NPG];      // 4 KB
    __shared__ float redc[16], redq[16];

    const int tid = threadIdx.x;

    if (blockIdx.x < 16) {
        //---------------- counting sort for graph bg ----------------
        const int bg = blockIdx.x;
        if (tid < KCL) hist[tid] = 0;
        __syncthreads();
        unsigned char c[4];
        #pragma unroll
        for (int i = 0; i < 4; ++i) {
            c[i] = clus[(bg << 12) + tid + (i << 10)];
            atomicAdd(&hist[c[i]], 1);
        }
        __syncthreads();
        if (tid < KCL) {
            int v = hist[tid], inc = v;
            #pragma unroll
            for (int off = 1; off < 64; off <<= 1) {
                int t = __shfl_up(inc, off);
                if (tid >= off) inc += t;
            }
            int excl = inc - v;
            offs[tid] = excl;
            counts[(bg << 6) + tid] = v;
            starts[(bg << 6) + tid] = excl;
        }
        __syncthreads();
        #pragma unroll
        for (int i = 0; i < 4; ++i) {
            int p = atomicAdd(&offs[c[i]], 1);
            order[(bg << 12) + p] = (unsigned short)(tid + (i << 10));
        }
    } else {
        //---------------- edge slice eb (4096 edges) ----------------
        const int eb = blockIdx.x - 16;
        const int bg = eb >> 4;
        ((float4*)adj)[tid] = make_float4(0.f, 0.f, 0.f, 0.f);
        ((int*)cl)[tid] = ((const int*)(clus + (size_t)bg * NPG))[tid];
        __syncthreads();

        const int e0 = eb << 12;
        float csum = 0.f, qsum = 0.f;
        #pragma unroll
        for (int it = 0; it < 4; ++it) {
            const int e = e0 + (it << 10) + tid;
            const int s = ei[e]         & (NPG - 1);   // graphs are 4096-aligned
            const int d = ei[NEDGE + e] & (NPG - 1);
            const float w = ew[e];
            const int ks = cl[s], kd = cl[d];
            atomicAdd(&adj[(ks << 6) + kd], w);
            csum += (ks == kd) ? w : 0.f;
            qsum += w * w;
        }
        #pragma unroll
        for (int off = 32; off > 0; off >>= 1) {
            csum += __shfl_down(csum, off);
            qsum += __shfl_down(qsum, off);
        }
        const int lane = tid & 63, wv = tid >> 6;
        if (lane == 0) { redc[wv] = csum; redq[wv] = qsum; }
        __syncthreads();   // also guarantees all LDS atomics into adj are done
        if (tid == 0) {
            float cs = 0.f, qs = 0.f;
            #pragma unroll
            for (int i = 0; i < 16; ++i) { cs += redc[i]; qs += redq[i]; }
            crossp[eb] = cs;
            asqp[eb]   = qs;
        }
        // push LDS adj tile into out_adj (zeroed by K1); skip empty cells
        float* oadj = out + 131072 + (bg << 12);
        #pragma unroll
        for (int i = 0; i < 4; ++i) {
            const int c = tid + (i << 10);
            const float v = adj[c];
            if (v != 0.f) atomicAdd(&oadj[c], v);
        }
    }
}

// ---------------------------------------------------------------------------
// K3: pool (blocks 0..1023)  ||  finalize (block 1024).
// ---------------------------------------------------------------------------
__global__ __launch_bounds__(256) void poolreduce_kernel(
    const float* __restrict__ x, const unsigned short* __restrict__ order,
    const int* __restrict__ counts, const int* __restrict__ starts,
    const float* __restrict__ crossp, const float* __restrict__ asqp,
    float* __restrict__ out)
{
    __shared__ unsigned short ord[NPG];
    __shared__ float4 part[8][32];
    __shared__ float links[16];

    const int tid = threadIdx.x;
    const int blk = blockIdx.x;

    if (blk < 1024) {
        //---------------- segment-sum pooling for (graph, cluster) ----------
        const int bg = blk >> 6, k = blk & 63;
        const int cnt = counts[blk], start = starts[blk];
        for (int i = tid; i < cnt; i += 256)
            ord[i] = order[(bg << 12) + start + i];
        __syncthreads();
        const int grp = tid >> 5, l32 = tid & 31;
        float4 acc = {0.f, 0.f, 0.f, 0.f};
        for (int i = grp; i < cnt; i += 8) {
            const float4* row = (const float4*)(x + (((size_t)(bg << 12) + ord[i]) << 7));
            float4 v = row[l32];
            acc.x += v.x; acc.y += v.y; acc.z += v.z; acc.w += v.w;
        }
        part[grp][l32] = acc;
        __syncthreads();
        if (grp == 0) {
            float4 s = part[0][l32];
            #pragma unroll
            for (int g = 1; g < 8; ++g) {
                float4 p = part[g][l32];
                s.x += p.x; s.y += p.y; s.z += p.z; s.w += p.w;
            }
            ((float4*)(out + ((size_t)(bg << 13) + (k << 7))))[l32] = s;
        }
    } else {
        //---------------- losses + constant outputs -------------------------
        if (tid < 16) {
            const int bg = tid;
            float s2 = 0.f;
            #pragma unroll 8
            for (int k = 0; k < 64; ++k) {
                float c = (float)counts[(bg << 6) + k];
                s2 = fmaf(c, c, s2);
            }
            float cs = 0.f, as = 0.f;
            #pragma unroll
            for (int sl = 0; sl < 16; ++sl) {
                cs += crossp[(bg << 4) + sl];
                as += asqp[(bg << 4) + sl];
            }
            links[bg] = sqrtf(fmaxf(as - 2.f * cs + s2, 0.f)) * (1.f / 65536.f);
        }
        __syncthreads();
        if (tid == 0) {
            float m = 0.f;
            #pragma unroll
            for (int i = 0; i < 16; ++i) m += links[i];
            out[196608] = m * (1.f / 16.f);   // link_loss
            out[196609] = 0.f;                // entropy_loss (exact 0 for one-hot)
        }
        #pragma unroll
        for (int r = 0; r < 4; ++r) {
            int i = tid + (r << 8);
            out[196610 + i] = (float)(i >> 6);            // batch
        }
        if (tid < 17) out[197634 + tid] = (float)(tid << 6);  // batch_ptr_out
    }
}

extern "C" void kernel_launch(void* const* d_in, const int* in_sizes, int n_in,
                              void* d_out, int out_size, void* d_ws, size_t ws_size,
                              hipStream_t stream) {
    const float* x    = (const float*)d_in[0];
    const float* W    = (const float*)d_in[1];
    const float* bias = (const float*)d_in[2];
    const float* ew   = (const float*)d_in[3];
    const float* gum  = (const float*)d_in[4];
    const int*   ei   = (const int*)  d_in[5];
    // d_in[6] = batch_ptr (int64) — unused, graphs are equal-sized

    float* out = (float*)d_out;
    char*  wsb = (char*)d_ws;

    unsigned char*  clus   = (unsigned char*) (wsb + WS_CLUS);
    int*            counts = (int*)           (wsb + WS_CNT);
    int*            starts = (int*)           (wsb + WS_START);
    float*          crossp = (float*)         (wsb + WS_CROSS);
    float*          asqp   = (float*)         (wsb + WS_ASQ);
    unsigned short* order  = (unsigned short*)(wsb + WS_ORDER);

    assign_kernel<<<NTOT / 64, 256, 0, stream>>>(x, W, bias, gum, clus, out);

    sortedge_kernel<<<16 + 256, 1024, 0, stream>>>(
        clus, ei, ew, counts, starts, order, out, crossp, asqp);

    poolreduce_kernel<<<1024 + 1, 256, 0, stream>>>(
        x, order, counts, starts, crossp, asqp, out);
}